// Round 18
// baseline (105.376 us; speedup 1.0000x reference)
//
#include <hip/hip_runtime.h>

typedef float f32x4 __attribute__((ext_vector_type(4)));
typedef float f32x16 __attribute__((ext_vector_type(16)));
typedef short s16x8 __attribute__((ext_vector_type(8)));
typedef _Float16 f16x8 __attribute__((ext_vector_type(8)));
typedef _Float16 f16x4 __attribute__((ext_vector_type(4)));
typedef _Float16 f16x2 __attribute__((ext_vector_type(2)));
typedef unsigned int u32;
typedef u32 u32x4 __attribute__((ext_vector_type(4)));
typedef unsigned short u16;

#define BB 4096
#define FF 50
#define PP 1225
#define XS 68          // xs (f32) row stride (Gram phase, overlaid region)
#define XH 72          // xh (f16) row stride: 144 B, 16B-aligned
#define GSC 52         // Gram col stride
#define TPB 256

struct f4q { f32x4 a, b, c, d; };

// split 8 f32 into packed bf16 hi + lo fragments (Gram phase only)
__device__ __forceinline__ void split_pack(f32x4 v0, f32x4 v1, s16x8& ph, s16x8& pl) {
    u32x4 u0 = __builtin_bit_cast(u32x4, v0), u1 = __builtin_bit_cast(u32x4, v1);
    u32x4 h0 = u0 & 0xFFFF0000u, h1 = u1 & 0xFFFF0000u;
    f32x4 lo0 = v0 - __builtin_bit_cast(f32x4, h0);
    f32x4 lo1 = v1 - __builtin_bit_cast(f32x4, h1);
    u32x4 l0 = __builtin_bit_cast(u32x4, lo0), l1 = __builtin_bit_cast(u32x4, lo1);
    u32x4 hp, lp;
    hp[0] = __builtin_amdgcn_perm(u0[1], u0[0], 0x07060302u);
    hp[1] = __builtin_amdgcn_perm(u0[3], u0[2], 0x07060302u);
    hp[2] = __builtin_amdgcn_perm(u1[1], u1[0], 0x07060302u);
    hp[3] = __builtin_amdgcn_perm(u1[3], u1[2], 0x07060302u);
    lp[0] = __builtin_amdgcn_perm(l0[1], l0[0], 0x07060302u);
    lp[1] = __builtin_amdgcn_perm(l0[3], l0[2], 0x07060302u);
    lp[2] = __builtin_amdgcn_perm(l1[1], l1[0], 0x07060302u);
    lp[3] = __builtin_amdgcn_perm(l1[3], l1[2], 0x07060302u);
    ph = __builtin_bit_cast(s16x8, hp);
    pl = __builtin_bit_cast(s16x8, lp);
}

__global__ __launch_bounds__(TPB, 2)
void afm_mfma(const float* __restrict__ g_x, const float* __restrict__ g_W1,
              const float* __restrict__ g_b1, const float* __restrict__ g_w2,
              const float* __restrict__ g_p, float* __restrict__ g_out)
{
    // union region: phase 1 holds xs (f32, 13600 B); phase 2 holds
    // Gs (10400 B) + ipkH (5120 B) + gof (2560 B) = 18080 B
    __shared__ __align__(16) char uni[18080];
    __shared__ __align__(16) _Float16 xh[FF * XH];       // 7200 B  (f16 RNE)
    __shared__ __align__(16) _Float16 wpk[512 * 8];      // 8192 B  W1 f16 frags
    __shared__ __align__(16) float b1s[64], w2s[64], ps[64];
    __shared__ float so_s[4], sw_s[4];

    float* xs        = (float*)uni;
    float* Gs        = (float*)uni;
    u32* ipkH        = (u32*)(uni + 10400);
    u16* gof         = (u16*)(uni + 15520);

    const int tid = threadIdx.x;
    const int b = blockIdx.x;
    const float* gxb = g_x + (size_t)b * FF * 64;

    // ---- stage x[b]: f32 (union region) + f16 RNE ----
    {
        const float4* gx4 = (const float4*)gxb;
        for (int i = tid; i < FF * 16; i += TPB) {
            float4 v = gx4[i];
            int row = i >> 4, col = (i & 15) << 2;
            *(float4*)&xs[row * XS + col] = v;
            f16x4 h = { (_Float16)v.x, (_Float16)v.y, (_Float16)v.z, (_Float16)v.w };
            *(f16x4*)&xh[row * XH + col] = h;
        }
    }
    if (tid < 64) { b1s[tid] = g_b1[tid]; w2s[tid] = g_w2[tid]; ps[tid] = g_p[tid]; }

    // ---- pack W1 into 32x32x16 A-fragment order, single f16 (RNE) ----
    // entry e=(ks,ma,ln): A[r=ma*32+(ln&31)][k=ks*16+(ln>>5)*8+j] = W1[k][r]
    for (int e = tid; e < 512; e += TPB) {
        int ks = e >> 7, ma = (e >> 6) & 1, ln = e & 63;
        int r = ma * 32 + (ln & 31);
        int k0 = ks * 16 + (ln >> 5) * 8;
        f16x8 h;
        #pragma unroll
        for (int j = 0; j < 8; ++j)
            h[j] = (_Float16)g_W1[(k0 + j) * 64 + r];
        *(f16x8*)&wpk[e * 8] = h;
    }
    __syncthreads();

    const int lane = tid & 63, wq = tid >> 6;
    const int rl = lane & 31, hi = lane >> 5;

    // ---- Gram phase: G = x . (x*p)^T from LDS xs ----
    {
        const int mi = wq >> 1, mj = wq & 1;
        int ra = mi * 32 + rl; ra = ra < FF ? ra : FF - 1;
        int rb = mj * 32 + rl; rb = rb < FF ? rb : FF - 1;
        f32x16 gacc;
        #pragma unroll
        for (int i = 0; i < 16; ++i) gacc[i] = 0.f;
        #pragma unroll
        for (int ks = 0; ks < 4; ++ks) {
            int d0 = ks * 16 + hi * 8;
            const float* xa = &xs[ra * XS + d0];
            const float* xb = &xs[rb * XS + d0];
            f32x4 a0 = *(const f32x4*)xa, a1 = *(const f32x4*)(xa + 4);
            f32x4 p0 = *(const f32x4*)&ps[d0], p1 = *(const f32x4*)&ps[d0 + 4];
            f32x4 b0 = *(const f32x4*)xb * p0, b1v = *(const f32x4*)(xb + 4) * p1;
            s16x8 ah, al, bh, bl;
            split_pack(a0, a1, ah, al);
            split_pack(b0, b1v, bh, bl);
            gacc = __builtin_amdgcn_mfma_f32_32x32x16_bf16(ah, bh, gacc, 0, 0, 0);
            gacc = __builtin_amdgcn_mfma_f32_32x32x16_bf16(al, bh, gacc, 0, 0, 0);
            gacc = __builtin_amdgcn_mfma_f32_32x32x16_bf16(ah, bl, gacc, 0, 0, 0);
        }
        __syncthreads();   // all xs reads complete before Gs/tables overwrite it
        #pragma unroll
        for (int r = 0; r < 16; ++r) {
            int row = mi * 32 + (r & 3) + 8 * (r >> 2) + 4 * hi;
            int col = mj * 32 + rl;
            if (row < FF && col < FF) Gs[row * GSC + col] = gacc[r];
        }
    }

    // ---- pair tables into the overlaid region (padded to 1280) ----
    for (int p = tid; p < 1280; p += TPB) {
        u32 va = 0; u16 vg = 0;
        if (p < PP) {
            int i = 0, base = 0;
            while (base + (FF - 1 - i) <= p) { base += FF - 1 - i; ++i; }
            int j = p - base + i + 1;
            va = (u32)(i * XH * 2) | ((u32)(j * XH * 2) << 16);
            vg = (u16)(i * GSC + j);
        }
        ipkH[p] = va; gof[p] = vg;
    }
    __syncthreads();

    // ---- persistent loop-invariants ----
    f4q cq0, cq1;
    cq0.a = *(const f32x4*)&b1s[      4 * hi];
    cq0.b = *(const f32x4*)&b1s[ 8 + 4 * hi];
    cq0.c = *(const f32x4*)&b1s[16 + 4 * hi];
    cq0.d = *(const f32x4*)&b1s[24 + 4 * hi];
    cq1.a = *(const f32x4*)&b1s[32 + 4 * hi];
    cq1.b = *(const f32x4*)&b1s[40 + 4 * hi];
    cq1.c = *(const f32x4*)&b1s[48 + 4 * hi];
    cq1.d = *(const f32x4*)&b1s[56 + 4 * hi];
    const f32x16 biasC0 = __builtin_bit_cast(f32x16, cq0);
    const f32x16 biasC1 = __builtin_bit_cast(f32x16, cq1);

    // w2 as packed f16 pairs matching acc reg layout: reg r -> a=(r&3)+8*(r>>2)+4*hi
    u32 w2q0[8], w2q1[8];
    #pragma unroll
    for (int q = 0; q < 8; ++q) {
        int a0 = ((2 * q) & 3) + 8 * (q >> 1) + 4 * hi;
        f16x2 p0 = { (_Float16)w2s[a0], (_Float16)w2s[a0 + 1] };
        f16x2 p1 = { (_Float16)w2s[32 + a0], (_Float16)w2s[32 + a0 + 1] };
        w2q0[q] = __builtin_bit_cast(u32, p0);
        w2q1[q] = __builtin_bit_cast(u32, p1);
    }

    const char* pW = (const char*)wpk + lane * 16;
    f16x8 wr[8];
    #pragma unroll
    for (int k8 = 0; k8 < 8; ++k8)
        wr[k8] = *(const f16x8*)(pW + k8 * 1024);

    float s_w = 0.f, s_out = 0.f;

    // ---- main loop: DUAL pair-blocks per wave-iteration (4 indep chains) ----
    for (int blk2 = wq * 2; blk2 < 40; blk2 += 8) {
        const int p0 = blk2 * 32 + rl;
        const int p1 = p0 + 32;
        const u32 q0 = ipkH[p0], q1 = ipkH[p1];
        const float gv0 = Gs[gof[p0]], gv1 = Gs[gof[p1]];
        const char* pA0 = (const char*)xh + (q0 & 0xFFFFu) + hi * 16;
        const char* pB0 = (const char*)xh + (q0 >> 16) + hi * 16;
        const char* pA1 = (const char*)xh + (q1 & 0xFFFFu) + hi * 16;
        const char* pB1 = (const char*)xh + (q1 >> 16) + hi * 16;

        f32x16 acc0, acc1, acc2, acc3;
        {
            f16x8 ph0 = *(const f16x8*)(pA0) * *(const f16x8*)(pB0);
            f16x8 ph1 = *(const f16x8*)(pA1) * *(const f16x8*)(pB1);
            acc0 = __builtin_amdgcn_mfma_f32_32x32x16_f16(wr[0], ph0, biasC0, 0, 0, 0);
            acc1 = __builtin_amdgcn_mfma_f32_32x32x16_f16(wr[1], ph0, biasC1, 0, 0, 0);
            acc2 = __builtin_amdgcn_mfma_f32_32x32x16_f16(wr[0], ph1, biasC0, 0, 0, 0);
            acc3 = __builtin_amdgcn_mfma_f32_32x32x16_f16(wr[1], ph1, biasC1, 0, 0, 0);
        }
        #pragma unroll
        for (int ks = 1; ks < 4; ++ks) {
            f16x8 ph0 = *(const f16x8*)(pA0 + ks * 32) * *(const f16x8*)(pB0 + ks * 32);
            f16x8 ph1 = *(const f16x8*)(pA1 + ks * 32) * *(const f16x8*)(pB1 + ks * 32);
            acc0 = __builtin_amdgcn_mfma_f32_32x32x16_f16(wr[ks * 2],     ph0, acc0, 0, 0, 0);
            acc1 = __builtin_amdgcn_mfma_f32_32x32x16_f16(wr[ks * 2 + 1], ph0, acc1, 0, 0, 0);
            acc2 = __builtin_amdgcn_mfma_f32_32x32x16_f16(wr[ks * 2],     ph1, acc2, 0, 0, 0);
            acc3 = __builtin_amdgcn_mfma_f32_32x32x16_f16(wr[ks * 2 + 1], ph1, acc3, 0, 0, 0);
        }

        // ---- logits for both blocks: packed relu + v_dot2_f32_f16 ----
        const f16x2 z2 = { (_Float16)0.f, (_Float16)0.f };
        float la0 = 0.f, la1 = 0.f, lb0 = 0.f, lb1 = 0.f;
        #pragma unroll
        for (int q8 = 0; q8 < 8; ++q8) {
            f16x2 h0 = __builtin_bit_cast(f16x2,
                __builtin_amdgcn_cvt_pkrtz(acc0[2 * q8], acc0[2 * q8 + 1]));
            f16x2 h1 = __builtin_bit_cast(f16x2,
                __builtin_amdgcn_cvt_pkrtz(acc1[2 * q8], acc1[2 * q8 + 1]));
            f16x2 h2 = __builtin_bit_cast(f16x2,
                __builtin_amdgcn_cvt_pkrtz(acc2[2 * q8], acc2[2 * q8 + 1]));
            f16x2 h3 = __builtin_bit_cast(f16x2,
                __builtin_amdgcn_cvt_pkrtz(acc3[2 * q8], acc3[2 * q8 + 1]));
            h0 = __builtin_elementwise_max(h0, z2);
            h1 = __builtin_elementwise_max(h1, z2);
            h2 = __builtin_elementwise_max(h2, z2);
            h3 = __builtin_elementwise_max(h3, z2);
            la0 = __builtin_amdgcn_fdot2(h0, __builtin_bit_cast(f16x2, w2q0[q8]), la0, false);
            la1 = __builtin_amdgcn_fdot2(h1, __builtin_bit_cast(f16x2, w2q1[q8]), la1, false);
            lb0 = __builtin_amdgcn_fdot2(h2, __builtin_bit_cast(f16x2, w2q0[q8]), lb0, false);
            lb1 = __builtin_amdgcn_fdot2(h3, __builtin_bit_cast(f16x2, w2q1[q8]), lb1, false);
        }
        float lg0 = la0 + la1;
        float lg1 = lb0 + lb1;
        lg0 += __shfl_xor(lg0, 32);
        lg1 += __shfl_xor(lg1, 32);

        // softmax without max subtraction (logits bounded ~|40| << 88)
        float e0 = (p0 < PP) ? __expf(lg0) : 0.f;
        float e1 = (p1 < PP) ? __expf(lg1) : 0.f;
        s_w += e0 + e1;
        s_out = fmaf(e0, gv0, fmaf(e1, gv1, s_out));
    }

    // ---- reduce over lanes, then waves ----
    #pragma unroll
    for (int off = 1; off < 32; off <<= 1) {
        s_w += __shfl_xor(s_w, off);
        s_out += __shfl_xor(s_out, off);
    }
    if (lane == 0) { sw_s[wq] = s_w; so_s[wq] = s_out; }
    __syncthreads();

    if (tid == 0) {
        float sg = sw_s[0] + sw_s[1] + sw_s[2] + sw_s[3];
        float so = so_s[0] + so_s[1] + so_s[2] + so_s[3];
        g_out[b] = so / sg;
    }
}

extern "C" void kernel_launch(void* const* d_in, const int* in_sizes, int n_in,
                              void* d_out, int out_size, void* d_ws, size_t ws_size,
                              hipStream_t stream) {
    const float* g_x  = (const float*)d_in[0];
    const float* g_W1 = (const float*)d_in[1];
    const float* g_b1 = (const float*)d_in[2];
    const float* g_w2 = (const float*)d_in[3];
    const float* g_p  = (const float*)d_in[4];
    float* g_out = (float*)d_out;
    afm_mfma<<<BB, TPB, 0, stream>>>(g_x, g_W1, g_b1, g_w2, g_p, g_out);
}

// Round 19
// 73.285 us; speedup vs baseline: 1.4379x; 1.4379x over previous
//
#include <hip/hip_runtime.h>

typedef float f32x4 __attribute__((ext_vector_type(4)));
typedef float f32x16 __attribute__((ext_vector_type(16)));
typedef short s16x8 __attribute__((ext_vector_type(8)));
typedef _Float16 f16x8 __attribute__((ext_vector_type(8)));
typedef _Float16 f16x4 __attribute__((ext_vector_type(4)));
typedef _Float16 f16x2 __attribute__((ext_vector_type(2)));
typedef unsigned int u32;
typedef u32 u32x4 __attribute__((ext_vector_type(4)));
typedef unsigned short u16;

#define BB 4096
#define FF 50
#define PP 1225
#define XS 68          // xs (f32) row stride (Gram phase, overlaid region)
#define XH 72          // xh (f16) row stride: 144 B, 16B-aligned
#define GSC 52         // Gram col stride
#define TPB 256

// d_ws layout: [0,8192) wpk f16 frags; [8192,13312) ipkH; [13312,15872) gof
#define WS_WPK  0
#define WS_TBL  8192           // ipkH (5120 B) + gof (2560 B), contiguous

struct f4q { f32x4 a, b, c, d; };

// split 8 f32 into packed bf16 hi + lo fragments (Gram phase only)
__device__ __forceinline__ void split_pack(f32x4 v0, f32x4 v1, s16x8& ph, s16x8& pl) {
    u32x4 u0 = __builtin_bit_cast(u32x4, v0), u1 = __builtin_bit_cast(u32x4, v1);
    u32x4 h0 = u0 & 0xFFFF0000u, h1 = u1 & 0xFFFF0000u;
    f32x4 lo0 = v0 - __builtin_bit_cast(f32x4, h0);
    f32x4 lo1 = v1 - __builtin_bit_cast(f32x4, h1);
    u32x4 l0 = __builtin_bit_cast(u32x4, lo0), l1 = __builtin_bit_cast(u32x4, lo1);
    u32x4 hp, lp;
    hp[0] = __builtin_amdgcn_perm(u0[1], u0[0], 0x07060302u);
    hp[1] = __builtin_amdgcn_perm(u0[3], u0[2], 0x07060302u);
    hp[2] = __builtin_amdgcn_perm(u1[1], u1[0], 0x07060302u);
    hp[3] = __builtin_amdgcn_perm(u1[3], u1[2], 0x07060302u);
    lp[0] = __builtin_amdgcn_perm(l0[1], l0[0], 0x07060302u);
    lp[1] = __builtin_amdgcn_perm(l0[3], l0[2], 0x07060302u);
    lp[2] = __builtin_amdgcn_perm(l1[1], l1[0], 0x07060302u);
    lp[3] = __builtin_amdgcn_perm(l1[3], l1[2], 0x07060302u);
    ph = __builtin_bit_cast(s16x8, hp);
    pl = __builtin_bit_cast(s16x8, lp);
}

// ---- setup kernel: pack W1 frags + pair tables into d_ws, once ----
__global__ __launch_bounds__(TPB)
void afm_setup(const float* __restrict__ g_W1, char* __restrict__ ws)
{
    _Float16* wpk = (_Float16*)(ws + WS_WPK);
    u32* ipkH     = (u32*)(ws + WS_TBL);
    u16* gof      = (u16*)(ws + WS_TBL + 5120);
    const int tid = threadIdx.x, bid = blockIdx.x;

    if (bid < 2) {
        int e = bid * 256 + tid;
        int ks = e >> 7, ma = (e >> 6) & 1, ln = e & 63;
        int r = ma * 32 + (ln & 31);
        int k0 = ks * 16 + (ln >> 5) * 8;
        f16x8 h;
        #pragma unroll
        for (int j = 0; j < 8; ++j)
            h[j] = (_Float16)g_W1[(k0 + j) * 64 + r];
        *(f16x8*)&wpk[e * 8] = h;
    } else {
        int p = (bid - 2) * 256 + tid;
        if (p < 1280) {
            u32 va = 0; u16 vg = 0;
            if (p < PP) {
                int i = 0, base = 0;
                while (base + (FF - 1 - i) <= p) { base += FF - 1 - i; ++i; }
                int j = p - base + i + 1;
                va = (u32)(i * XH * 2) | ((u32)(j * XH * 2) << 16);
                vg = (u16)(i * GSC + j);
            }
            ipkH[p] = va; gof[p] = vg;
        }
    }
}

__global__ __launch_bounds__(TPB, 2)
void afm_mfma(const float* __restrict__ g_x, const float* __restrict__ g_b1,
              const float* __restrict__ g_w2, const float* __restrict__ g_p,
              const char* __restrict__ ws, float* __restrict__ g_out)
{
    // union region: phase 1 holds xs (f32, 13600 B); phase 2 holds
    // Gs (10400 B) + ipkH (5120 B) + gof (2560 B) = 18080 B
    __shared__ __align__(16) char uni[18080];
    __shared__ __align__(16) _Float16 xh[FF * XH];       // 7200 B  (f16 RNE)
    __shared__ __align__(16) _Float16 wpk[512 * 8];      // 8192 B  W1 f16 frags
    __shared__ __align__(16) float b1s[64], w2s[64], ps[64];
    __shared__ float so_s[4], sw_s[4];

    float* xs        = (float*)uni;
    float* Gs        = (float*)uni;
    u32* ipkH        = (u32*)(uni + 10400);
    u16* gof         = (u16*)(uni + 15520);

    const int tid = threadIdx.x;
    const int b = blockIdx.x;
    const float* gxb = g_x + (size_t)b * FF * 64;

    // ---- stage x[b]: f32 (union region) + f16 RNE; copy wpk from ws ----
    {
        const float4* gx4 = (const float4*)gxb;
        for (int i = tid; i < FF * 16; i += TPB) {
            float4 v = gx4[i];
            int row = i >> 4, col = (i & 15) << 2;
            *(float4*)&xs[row * XS + col] = v;
            f16x4 h = { (_Float16)v.x, (_Float16)v.y, (_Float16)v.z, (_Float16)v.w };
            *(f16x4*)&xh[row * XH + col] = h;
        }
        const float4* wsrc = (const float4*)(ws + WS_WPK);
        float4* wdst = (float4*)wpk;
        for (int i = tid; i < 512; i += TPB) wdst[i] = wsrc[i];
    }
    if (tid < 64) { b1s[tid] = g_b1[tid]; w2s[tid] = g_w2[tid]; ps[tid] = g_p[tid]; }
    __syncthreads();

    const int lane = tid & 63, wq = tid >> 6;
    const int rl = lane & 31, hi = lane >> 5;

    // ---- Gram phase: G = x . (x*p)^T from LDS xs ----
    {
        const int mi = wq >> 1, mj = wq & 1;
        int ra = mi * 32 + rl; ra = ra < FF ? ra : FF - 1;
        int rb = mj * 32 + rl; rb = rb < FF ? rb : FF - 1;
        f32x16 gacc;
        #pragma unroll
        for (int i = 0; i < 16; ++i) gacc[i] = 0.f;
        #pragma unroll
        for (int ks = 0; ks < 4; ++ks) {
            int d0 = ks * 16 + hi * 8;
            const float* xa = &xs[ra * XS + d0];
            const float* xb = &xs[rb * XS + d0];
            f32x4 a0 = *(const f32x4*)xa, a1 = *(const f32x4*)(xa + 4);
            f32x4 p0 = *(const f32x4*)&ps[d0], p1 = *(const f32x4*)&ps[d0 + 4];
            f32x4 b0 = *(const f32x4*)xb * p0, b1v = *(const f32x4*)(xb + 4) * p1;
            s16x8 ah, al, bh, bl;
            split_pack(a0, a1, ah, al);
            split_pack(b0, b1v, bh, bl);
            gacc = __builtin_amdgcn_mfma_f32_32x32x16_bf16(ah, bh, gacc, 0, 0, 0);
            gacc = __builtin_amdgcn_mfma_f32_32x32x16_bf16(al, bh, gacc, 0, 0, 0);
            gacc = __builtin_amdgcn_mfma_f32_32x32x16_bf16(ah, bl, gacc, 0, 0, 0);
        }
        __syncthreads();   // all xs reads complete before Gs/tables overwrite it
        #pragma unroll
        for (int r = 0; r < 16; ++r) {
            int row = mi * 32 + (r & 3) + 8 * (r >> 2) + 4 * hi;
            int col = mj * 32 + rl;
            if (row < FF && col < FF) Gs[row * GSC + col] = gacc[r];
        }
    }

    // ---- bulk-copy pair tables from ws into the overlaid region ----
    {
        const float4* tsrc = (const float4*)(ws + WS_TBL);
        float4* tdst = (float4*)(uni + 10400);
        for (int i = tid; i < 480; i += TPB) tdst[i] = tsrc[i];   // 7680 B
    }
    __syncthreads();

    // ---- persistent loop-invariants ----
    f4q cq0, cq1;
    cq0.a = *(const f32x4*)&b1s[      4 * hi];
    cq0.b = *(const f32x4*)&b1s[ 8 + 4 * hi];
    cq0.c = *(const f32x4*)&b1s[16 + 4 * hi];
    cq0.d = *(const f32x4*)&b1s[24 + 4 * hi];
    cq1.a = *(const f32x4*)&b1s[32 + 4 * hi];
    cq1.b = *(const f32x4*)&b1s[40 + 4 * hi];
    cq1.c = *(const f32x4*)&b1s[48 + 4 * hi];
    cq1.d = *(const f32x4*)&b1s[56 + 4 * hi];
    const f32x16 biasC0 = __builtin_bit_cast(f32x16, cq0);
    const f32x16 biasC1 = __builtin_bit_cast(f32x16, cq1);

    // w2 as packed f16 pairs matching acc reg layout: reg r -> a=(r&3)+8*(r>>2)+4*hi
    u32 w2q0[8], w2q1[8];
    #pragma unroll
    for (int q = 0; q < 8; ++q) {
        int a0 = ((2 * q) & 3) + 8 * (q >> 1) + 4 * hi;
        f16x2 p0 = { (_Float16)w2s[a0], (_Float16)w2s[a0 + 1] };
        f16x2 p1 = { (_Float16)w2s[32 + a0], (_Float16)w2s[32 + a0 + 1] };
        w2q0[q] = __builtin_bit_cast(u32, p0);
        w2q1[q] = __builtin_bit_cast(u32, p1);
    }

    const char* pW = (const char*)wpk + lane * 16;
    f16x8 wr[8];
    #pragma unroll
    for (int k8 = 0; k8 < 8; ++k8)
        wr[k8] = *(const f16x8*)(pW + k8 * 1024);

    float s_w = 0.f, s_out = 0.f;

    // ---- main loop: per-wave independent 32-pair blocks, no barriers ----
    for (int blk = wq; blk < 39; blk += 4) {
        const int p = blk * 32 + rl;
        const u32 q = ipkH[p];
        const float gval = Gs[gof[p]];
        const char* pA = (const char*)xh + (q & 0xFFFFu) + hi * 16;
        const char* pB = (const char*)xh + (q >> 16) + hi * 16;

        f32x16 acc0, acc1;
        // ks = 0: bias as C; prod formed directly in f16 (v_pk_mul_f16)
        {
            f16x8 ph = *(const f16x8*)(pA) * *(const f16x8*)(pB);
            acc0 = __builtin_amdgcn_mfma_f32_32x32x16_f16(wr[0], ph, biasC0, 0, 0, 0);
            acc1 = __builtin_amdgcn_mfma_f32_32x32x16_f16(wr[1], ph, biasC1, 0, 0, 0);
        }
        #pragma unroll
        for (int ks = 1; ks < 4; ++ks) {
            f16x8 ph = *(const f16x8*)(pA + ks * 32) * *(const f16x8*)(pB + ks * 32);
            acc0 = __builtin_amdgcn_mfma_f32_32x32x16_f16(wr[ks * 2],     ph, acc0, 0, 0, 0);
            acc1 = __builtin_amdgcn_mfma_f32_32x32x16_f16(wr[ks * 2 + 1], ph, acc1, 0, 0, 0);
        }

        // ---- logits: packed relu + v_dot2_f32_f16 (bias already in acc) ----
        const f16x2 z2 = { (_Float16)0.f, (_Float16)0.f };
        float l0 = 0.f, l1 = 0.f, l2 = 0.f, l3 = 0.f;
        #pragma unroll
        for (int q8 = 0; q8 < 8; ++q8) {
            f16x2 h0 = __builtin_bit_cast(f16x2,
                __builtin_amdgcn_cvt_pkrtz(acc0[2 * q8], acc0[2 * q8 + 1]));
            f16x2 h1 = __builtin_bit_cast(f16x2,
                __builtin_amdgcn_cvt_pkrtz(acc1[2 * q8], acc1[2 * q8 + 1]));
            h0 = __builtin_elementwise_max(h0, z2);
            h1 = __builtin_elementwise_max(h1, z2);
            float& d0 = (q8 & 1) ? l1 : l0;
            float& d1 = (q8 & 1) ? l3 : l2;
            d0 = __builtin_amdgcn_fdot2(h0, __builtin_bit_cast(f16x2, w2q0[q8]), d0, false);
            d1 = __builtin_amdgcn_fdot2(h1, __builtin_bit_cast(f16x2, w2q1[q8]), d1, false);
        }
        float lg = (l0 + l1) + (l2 + l3);
        lg += __shfl_xor(lg, 32);

        // softmax without max subtraction (logits bounded ~|40| << 88)
        float e = (p < PP) ? __expf(lg) : 0.f;
        s_w += e;
        s_out = fmaf(e, gval, s_out);
    }

    // ---- reduce over lanes, then waves ----
    #pragma unroll
    for (int off = 1; off < 32; off <<= 1) {
        s_w += __shfl_xor(s_w, off);
        s_out += __shfl_xor(s_out, off);
    }
    if (lane == 0) { sw_s[wq] = s_w; so_s[wq] = s_out; }
    __syncthreads();

    if (tid == 0) {
        float sg = sw_s[0] + sw_s[1] + sw_s[2] + sw_s[3];
        float so = so_s[0] + so_s[1] + so_s[2] + so_s[3];
        g_out[b] = so / sg;
    }
}

extern "C" void kernel_launch(void* const* d_in, const int* in_sizes, int n_in,
                              void* d_out, int out_size, void* d_ws, size_t ws_size,
                              hipStream_t stream) {
    const float* g_x  = (const float*)d_in[0];
    const float* g_W1 = (const float*)d_in[1];
    const float* g_b1 = (const float*)d_in[2];
    const float* g_w2 = (const float*)d_in[3];
    const float* g_p  = (const float*)d_in[4];
    float* g_out = (float*)d_out;
    char* ws = (char*)d_ws;
    afm_setup<<<7, TPB, 0, stream>>>(g_W1, ws);
    afm_mfma<<<BB, TPB, 0, stream>>>(g_x, g_b1, g_w2, g_p, ws, g_out);
}

// Round 20
// 73.089 us; speedup vs baseline: 1.4417x; 1.0027x over previous
//
#include <hip/hip_runtime.h>

typedef float f32x4 __attribute__((ext_vector_type(4)));
typedef float f32x16 __attribute__((ext_vector_type(16)));
typedef short s16x8 __attribute__((ext_vector_type(8)));
typedef _Float16 f16x8 __attribute__((ext_vector_type(8)));
typedef _Float16 f16x4 __attribute__((ext_vector_type(4)));
typedef _Float16 f16x2 __attribute__((ext_vector_type(2)));
typedef unsigned int u32;
typedef u32 u32x4 __attribute__((ext_vector_type(4)));
typedef unsigned short u16;

#define BB 4096
#define FF 50
#define PP 1225
#define XS 68          // xs (f32) row stride (Gram phase, overlaid region)
#define XH 72          // xh (f16) row stride: 144 B, 16B-aligned
#define GSC 52         // Gram col stride
#define TPB 256

// d_ws layout: [0,8192) wpk f16 frags; [8192,13312) ipkH; [13312,15872) gof
#define WS_WPK  0
#define WS_TBL  8192

struct f4q { f32x4 a, b, c, d; };

// split 8 f32 into packed bf16 hi + lo fragments (Gram phase only)
__device__ __forceinline__ void split_pack(f32x4 v0, f32x4 v1, s16x8& ph, s16x8& pl) {
    u32x4 u0 = __builtin_bit_cast(u32x4, v0), u1 = __builtin_bit_cast(u32x4, v1);
    u32x4 h0 = u0 & 0xFFFF0000u, h1 = u1 & 0xFFFF0000u;
    f32x4 lo0 = v0 - __builtin_bit_cast(f32x4, h0);
    f32x4 lo1 = v1 - __builtin_bit_cast(f32x4, h1);
    u32x4 l0 = __builtin_bit_cast(u32x4, lo0), l1 = __builtin_bit_cast(u32x4, lo1);
    u32x4 hp, lp;
    hp[0] = __builtin_amdgcn_perm(u0[1], u0[0], 0x07060302u);
    hp[1] = __builtin_amdgcn_perm(u0[3], u0[2], 0x07060302u);
    hp[2] = __builtin_amdgcn_perm(u1[1], u1[0], 0x07060302u);
    hp[3] = __builtin_amdgcn_perm(u1[3], u1[2], 0x07060302u);
    lp[0] = __builtin_amdgcn_perm(l0[1], l0[0], 0x07060302u);
    lp[1] = __builtin_amdgcn_perm(l0[3], l0[2], 0x07060302u);
    lp[2] = __builtin_amdgcn_perm(l1[1], l1[0], 0x07060302u);
    lp[3] = __builtin_amdgcn_perm(l1[3], l1[2], 0x07060302u);
    ph = __builtin_bit_cast(s16x8, hp);
    pl = __builtin_bit_cast(s16x8, lp);
}

// ---- setup kernel: pack W1 frags + pair tables into d_ws, once ----
__global__ __launch_bounds__(TPB)
void afm_setup(const float* __restrict__ g_W1, char* __restrict__ ws)
{
    _Float16* wpk = (_Float16*)(ws + WS_WPK);
    u32* ipkH     = (u32*)(ws + WS_TBL);
    u16* gof      = (u16*)(ws + WS_TBL + 5120);
    const int tid = threadIdx.x, bid = blockIdx.x;

    if (bid < 2) {
        int e = bid * 256 + tid;
        int ks = e >> 7, ma = (e >> 6) & 1, ln = e & 63;
        int r = ma * 32 + (ln & 31);
        int k0 = ks * 16 + (ln >> 5) * 8;
        f16x8 h;
        #pragma unroll
        for (int j = 0; j < 8; ++j)
            h[j] = (_Float16)g_W1[(k0 + j) * 64 + r];
        *(f16x8*)&wpk[e * 8] = h;
    } else {
        int p = (bid - 2) * 256 + tid;
        if (p < 1280) {
            u32 va = 0; u16 vg = 0;
            if (p < PP) {
                int i = 0, base = 0;
                while (base + (FF - 1 - i) <= p) { base += FF - 1 - i; ++i; }
                int j = p - base + i + 1;
                va = (u32)(i * XH * 2) | ((u32)(j * XH * 2) << 16);
                vg = (u16)(i * GSC + j);
            }
            ipkH[p] = va; gof[p] = vg;
        }
    }
}

__global__ __launch_bounds__(TPB, 2)
void afm_mfma(const float* __restrict__ g_x, const float* __restrict__ g_b1,
              const float* __restrict__ g_w2, const float* __restrict__ g_p,
              const char* __restrict__ ws, float* __restrict__ g_out)
{
    // union region: per batch, phase A holds xs (f32, 13600 B); phase B holds Gs (10400 B)
    __shared__ __align__(16) char uni[13600];
    __shared__ __align__(16) char tblm[7680];            // ipkH (5120) + gof (2560), persistent
    __shared__ __align__(16) _Float16 xh[FF * XH];       // 7200 B  (f16 RNE)
    __shared__ __align__(16) _Float16 wpk[512 * 8];      // 8192 B  W1 f16 frags
    __shared__ __align__(16) float b1s[64], w2s[64], ps[64];
    __shared__ float so_s[4], sw_s[4];
    // ~37.6 KB

    float* xs   = (float*)uni;
    float* Gs   = (float*)uni;
    u32* ipkH   = (u32*)tblm;
    u16* gof    = (u16*)(tblm + 5120);

    const int tid = threadIdx.x;

    // ---- shared setup: copy wpk + tables from ws, load small vectors ----
    {
        const float4* wsrc = (const float4*)(ws + WS_WPK);
        float4* wdst = (float4*)wpk;
        for (int i = tid; i < 512; i += TPB) wdst[i] = wsrc[i];
        const float4* tsrc = (const float4*)(ws + WS_TBL);
        float4* tdst = (float4*)tblm;
        for (int i = tid; i < 480; i += TPB) tdst[i] = tsrc[i];
    }
    if (tid < 64) { b1s[tid] = g_b1[tid]; w2s[tid] = g_w2[tid]; ps[tid] = g_p[tid]; }
    __syncthreads();

    const int lane = tid & 63, wq = tid >> 6;
    const int rl = lane & 31, hi = lane >> 5;

    // ---- persistent loop-invariants (shared across both batches) ----
    f4q cq0, cq1;
    cq0.a = *(const f32x4*)&b1s[      4 * hi];
    cq0.b = *(const f32x4*)&b1s[ 8 + 4 * hi];
    cq0.c = *(const f32x4*)&b1s[16 + 4 * hi];
    cq0.d = *(const f32x4*)&b1s[24 + 4 * hi];
    cq1.a = *(const f32x4*)&b1s[32 + 4 * hi];
    cq1.b = *(const f32x4*)&b1s[40 + 4 * hi];
    cq1.c = *(const f32x4*)&b1s[48 + 4 * hi];
    cq1.d = *(const f32x4*)&b1s[56 + 4 * hi];
    const f32x16 biasC0 = __builtin_bit_cast(f32x16, cq0);
    const f32x16 biasC1 = __builtin_bit_cast(f32x16, cq1);

    u32 w2q0[8], w2q1[8];
    #pragma unroll
    for (int q = 0; q < 8; ++q) {
        int a0 = ((2 * q) & 3) + 8 * (q >> 1) + 4 * hi;
        f16x2 p0 = { (_Float16)w2s[a0], (_Float16)w2s[a0 + 1] };
        f16x2 p1 = { (_Float16)w2s[32 + a0], (_Float16)w2s[32 + a0 + 1] };
        w2q0[q] = __builtin_bit_cast(u32, p0);
        w2q1[q] = __builtin_bit_cast(u32, p1);
    }

    const char* pW = (const char*)wpk + lane * 16;
    f16x8 wr[8];
    #pragma unroll
    for (int k8 = 0; k8 < 8; ++k8)
        wr[k8] = *(const f16x8*)(pW + k8 * 1024);

    // ---- two batches per block, sequential ----
    #pragma unroll 1
    for (int sub = 0; sub < 2; ++sub) {
        const int bat = 2 * blockIdx.x + sub;
        const float* gxb = g_x + (size_t)bat * FF * 64;

        // ---- stage x[bat]: f32 (union) + f16 RNE ----
        {
            const float4* gx4 = (const float4*)gxb;
            for (int i = tid; i < FF * 16; i += TPB) {
                float4 v = gx4[i];
                int row = i >> 4, col = (i & 15) << 2;
                *(float4*)&xs[row * XS + col] = v;
                f16x4 h = { (_Float16)v.x, (_Float16)v.y, (_Float16)v.z, (_Float16)v.w };
                *(f16x4*)&xh[row * XH + col] = h;
            }
        }
        __syncthreads();

        // ---- Gram phase: G = x . (x*p)^T from LDS xs ----
        {
            const int mi = wq >> 1, mj = wq & 1;
            int ra = mi * 32 + rl; ra = ra < FF ? ra : FF - 1;
            int rb = mj * 32 + rl; rb = rb < FF ? rb : FF - 1;
            f32x16 gacc;
            #pragma unroll
            for (int i = 0; i < 16; ++i) gacc[i] = 0.f;
            #pragma unroll
            for (int ks = 0; ks < 4; ++ks) {
                int d0 = ks * 16 + hi * 8;
                const float* xa = &xs[ra * XS + d0];
                const float* xb = &xs[rb * XS + d0];
                f32x4 a0 = *(const f32x4*)xa, a1 = *(const f32x4*)(xa + 4);
                f32x4 p0 = *(const f32x4*)&ps[d0], p1 = *(const f32x4*)&ps[d0 + 4];
                f32x4 b0 = *(const f32x4*)xb * p0, b1v = *(const f32x4*)(xb + 4) * p1;
                s16x8 ah, al, bh, bl;
                split_pack(a0, a1, ah, al);
                split_pack(b0, b1v, bh, bl);
                gacc = __builtin_amdgcn_mfma_f32_32x32x16_bf16(ah, bh, gacc, 0, 0, 0);
                gacc = __builtin_amdgcn_mfma_f32_32x32x16_bf16(al, bh, gacc, 0, 0, 0);
                gacc = __builtin_amdgcn_mfma_f32_32x32x16_bf16(ah, bl, gacc, 0, 0, 0);
            }
            __syncthreads();   // xs reads done before Gs overwrites the union
            #pragma unroll
            for (int r = 0; r < 16; ++r) {
                int row = mi * 32 + (r & 3) + 8 * (r >> 2) + 4 * hi;
                int col = mj * 32 + rl;
                if (row < FF && col < FF) Gs[row * GSC + col] = gacc[r];
            }
        }
        __syncthreads();

        float s_w = 0.f, s_out = 0.f;

        // ---- main loop: per-wave independent 32-pair blocks, no barriers ----
        for (int blk = wq; blk < 39; blk += 4) {
            const int p = blk * 32 + rl;
            const u32 q = ipkH[p];
            const float gval = Gs[gof[p]];
            const char* pA = (const char*)xh + (q & 0xFFFFu) + hi * 16;
            const char* pB = (const char*)xh + (q >> 16) + hi * 16;

            f32x16 acc0, acc1;
            {
                f16x8 ph = *(const f16x8*)(pA) * *(const f16x8*)(pB);
                acc0 = __builtin_amdgcn_mfma_f32_32x32x16_f16(wr[0], ph, biasC0, 0, 0, 0);
                acc1 = __builtin_amdgcn_mfma_f32_32x32x16_f16(wr[1], ph, biasC1, 0, 0, 0);
            }
            #pragma unroll
            for (int ks = 1; ks < 4; ++ks) {
                f16x8 ph = *(const f16x8*)(pA + ks * 32) * *(const f16x8*)(pB + ks * 32);
                acc0 = __builtin_amdgcn_mfma_f32_32x32x16_f16(wr[ks * 2],     ph, acc0, 0, 0, 0);
                acc1 = __builtin_amdgcn_mfma_f32_32x32x16_f16(wr[ks * 2 + 1], ph, acc1, 0, 0, 0);
            }

            // ---- logits: packed relu + v_dot2_f32_f16 (bias already in acc) ----
            const f16x2 z2 = { (_Float16)0.f, (_Float16)0.f };
            float l0 = 0.f, l1 = 0.f, l2 = 0.f, l3 = 0.f;
            #pragma unroll
            for (int q8 = 0; q8 < 8; ++q8) {
                f16x2 h0 = __builtin_bit_cast(f16x2,
                    __builtin_amdgcn_cvt_pkrtz(acc0[2 * q8], acc0[2 * q8 + 1]));
                f16x2 h1 = __builtin_bit_cast(f16x2,
                    __builtin_amdgcn_cvt_pkrtz(acc1[2 * q8], acc1[2 * q8 + 1]));
                h0 = __builtin_elementwise_max(h0, z2);
                h1 = __builtin_elementwise_max(h1, z2);
                float& d0 = (q8 & 1) ? l1 : l0;
                float& d1 = (q8 & 1) ? l3 : l2;
                d0 = __builtin_amdgcn_fdot2(h0, __builtin_bit_cast(f16x2, w2q0[q8]), d0, false);
                d1 = __builtin_amdgcn_fdot2(h1, __builtin_bit_cast(f16x2, w2q1[q8]), d1, false);
            }
            float lg = (l0 + l1) + (l2 + l3);
            lg += __shfl_xor(lg, 32);

            // softmax without max subtraction (logits bounded ~|40| << 88)
            float e = (p < PP) ? __expf(lg) : 0.f;
            s_w += e;
            s_out = fmaf(e, gval, s_out);
        }

        // ---- reduce over lanes, then waves ----
        #pragma unroll
        for (int off = 1; off < 32; off <<= 1) {
            s_w += __shfl_xor(s_w, off);
            s_out += __shfl_xor(s_out, off);
        }
        if (lane == 0) { sw_s[wq] = s_w; so_s[wq] = s_out; }
        __syncthreads();

        if (tid == 0) {
            float sg = sw_s[0] + sw_s[1] + sw_s[2] + sw_s[3];
            float so = so_s[0] + so_s[1] + so_s[2] + so_s[3];
            g_out[bat] = so / sg;
        }
        __syncthreads();   // so_s consumed; safe to re-stage union next batch
    }
}

extern "C" void kernel_launch(void* const* d_in, const int* in_sizes, int n_in,
                              void* d_out, int out_size, void* d_ws, size_t ws_size,
                              hipStream_t stream) {
    const float* g_x  = (const float*)d_in[0];
    const float* g_W1 = (const float*)d_in[1];
    const float* g_b1 = (const float*)d_in[2];
    const float* g_w2 = (const float*)d_in[3];
    const float* g_p  = (const float*)d_in[4];
    float* g_out = (float*)d_out;
    char* ws = (char*)d_ws;
    afm_setup<<<7, TPB, 0, stream>>>(g_W1, ws);
    afm_mfma<<<BB / 2, TPB, 0, stream>>>(g_x, g_b1, g_w2, g_p, ws, g_out);
}